// Round 12
// baseline (253.891 us; speedup 1.0000x reference)
//
#include <hip/hip_runtime.h>
#include <math.h>

#define IN_F 128
#define OUT_F 32
#define HEADS 4
#define HC 128  // HEADS*OUT_F
#define NEG_SLOPE 0.2f
#define LOG2E 1.44269504088896f
#define ALD 136  // padded LDS A-row stride in bf16 (17408 B total)
#define FLD 68   // same buffer viewed as float rows (68*4 == 136*2)

typedef short bf16x8 __attribute__((ext_vector_type(8)));
typedef float f32x4 __attribute__((ext_vector_type(4)));

__device__ __forceinline__ unsigned short f2bf(float f) {  // RNE fp32->bf16
    unsigned u = __float_as_uint(f);
    u += 0x7FFFu + ((u >> 16) & 1u);
    return (unsigned short)(u >> 16);
}

// ---------------------------------------------------------------------------
// 0) prep: Wt[n][k] = bf16(concat(Wl,Wr)[k][n])  (B-operand, 64 KB, L2-hot)
//    + zero deg|fill|cursor (must precede proj's folded hist atomics).
// ---------------------------------------------------------------------------
__global__ void __launch_bounds__(256)
prep_kernel(const float* __restrict__ Wl, const float* __restrict__ Wr,
            unsigned short* __restrict__ Wt,
            int* __restrict__ zero_region, int zero_cnt) {
    const int t0 = blockIdx.x * 256 + threadIdx.x;
    const int stride = gridDim.x * 256;
    for (int i = t0; i < 256 * IN_F; i += stride) {
        const int n = i >> 7, k = i & 127;
        const float v = (n < 128) ? Wl[k * 128 + n] : Wr[k * 128 + (n - 128)];
        Wt[i] = f2bf(v);
    }
    for (int i = t0; i < zero_cnt; i += stride) zero_region[i] = 0;
}

// ---------------------------------------------------------------------------
// 1) Projection via MFMA bf16 + LDS-transpose epilogue for coalesced stores.
//    64-row tile / block (4 waves x 16 rows).  R11 post-mortem: scattered
//    2B/4B C-layout stores caused 1.63x write amplification and 75 us of
//    memory-wait (VALU 3.4%, Mfma 1.6%).  Epilogue now round-trips through
//    the 17.4 KB As buffer and emits dense 16B stores (256B/16-lane group).
// ---------------------------------------------------------------------------
__global__ void __launch_bounds__(256)
proj_kernel(const float* __restrict__ x,
            const unsigned short* __restrict__ Wt,
            unsigned short* __restrict__ xlb,
            float* __restrict__ xr, int N,
            const int* __restrict__ ei, int* __restrict__ deg,
            int E0, int Etot) {
    __shared__ unsigned short As[64 * ALD];
    float* Asf = (float*)As;  // aliased float view, stride FLD
    const int tid = threadIdx.x;

    // folded histogram: atomics overlap the staging + MFMA below
    for (int t = blockIdx.x * 256 + tid; t < Etot; t += gridDim.x * 256) {
        const int dst = (t < E0) ? ei[E0 + t] : (t - E0);
        atomicAdd(&deg[dst], 1);
    }

    const int n0 = blockIdx.x * 64;
    const int rows = min(64, N - n0);
#pragma unroll
    for (int q = 0; q < 8; ++q) {
        const int idx = q * 256 + tid;       // float4 index over 64x128 tile
        const int row = idx >> 5;
        const int col4 = (idx & 31) * 4;
        const float4 v = *(const float4*)&x[(size_t)min(n0 + row, N - 1) * IN_F + col4];
        ushort4 p;
        p.x = f2bf(v.x); p.y = f2bf(v.y); p.z = f2bf(v.z); p.w = f2bf(v.w);
        *(ushort4*)&As[row * ALD + col4] = p;
    }
    __syncthreads();

    const int w = tid >> 6, lane = tid & 63;
    const int lm = lane & 15, lg = lane >> 4;

    bf16x8 af[4];
#pragma unroll
    for (int kk = 0; kk < 4; ++kk)
        af[kk] = *(const bf16x8*)&As[(w * 16 + lm) * ALD + kk * 32 + lg * 8];

    f32x4 acc[16];
#pragma unroll
    for (int c = 0; c < 16; ++c) acc[c] = (f32x4){0.f, 0.f, 0.f, 0.f};

#pragma unroll
    for (int c = 0; c < 16; ++c) {
#pragma unroll
        for (int kk = 0; kk < 4; ++kk) {
            const bf16x8 bf = *(const bf16x8*)&Wt[(size_t)(c * 16 + lm) * 128 + kk * 32 + lg * 8];
            acc[c] = __builtin_amdgcn_mfma_f32_16x16x32_bf16(af[kk], bf, acc[c], 0, 0, 0);
        }
    }

    // ---- epilogue phase A: bf16 xl (cols 0..127), via LDS transpose ----
    const int orow = w * 16 + lg * 4;  // + r
    __syncthreads();                   // done reading As as A-operand
#pragma unroll
    for (int c = 0; c < 8; ++c)
#pragma unroll
        for (int r = 0; r < 4; ++r)
            As[(orow + r) * ALD + c * 16 + lm] = f2bf(acc[c][r]);
    __syncthreads();
#pragma unroll
    for (int it = 0; it < 4; ++it) {
        const int idx = it * 256 + tid;   // 0..1023
        const int row = idx >> 4;         // 0..63
        const int c8 = (idx & 15) * 8;    // ushort8 col start
        if (row < rows)
            *(bf16x8*)&xlb[(size_t)(n0 + row) * HC + c8] =
                *(const bf16x8*)&As[row * ALD + c8];
    }

    // ---- epilogue phase B: fp32 xr (cols 0..127), two 64-col half-passes ----
#pragma unroll
    for (int half = 0; half < 2; ++half) {
        __syncthreads();
#pragma unroll
        for (int c = 0; c < 4; ++c) {
            const int cc = 8 + half * 4 + c;
#pragma unroll
            for (int r = 0; r < 4; ++r)
                Asf[(orow + r) * FLD + c * 16 + lm] = acc[cc][r];
        }
        __syncthreads();
#pragma unroll
        for (int it = 0; it < 4; ++it) {
            const int idx = it * 256 + tid;  // 64 rows x 16 float4
            const int row = idx >> 4;
            const int c4 = (idx & 15) * 4;
            if (row < rows)
                *(float4*)&xr[(size_t)(n0 + row) * HC + half * 64 + c4] =
                    *(const float4*)&Asf[row * FLD + c4];
        }
    }
}

// ---------------------------------------------------------------------------
// 2) CSR build (hist folded into proj; zero folded into prep)
// ---------------------------------------------------------------------------
__global__ void alloc_kernel(const int* __restrict__ deg,
                             int* __restrict__ start,
                             unsigned int* __restrict__ cursor, int N) {
    __shared__ int sc[256];
    __shared__ int base_s;
    const int tid = threadIdx.x;
    const int n = blockIdx.x * 256 + tid;
    const int d = (n < N) ? deg[n] : 0;
    sc[tid] = d;
    __syncthreads();
#pragma unroll
    for (int off = 1; off < 256; off <<= 1) {
        int v = (tid >= off) ? sc[tid - off] : 0;
        __syncthreads();
        sc[tid] += v;
        __syncthreads();
    }
    if (tid == 255) base_s = (int)atomicAdd(cursor, (unsigned int)sc[255]);
    __syncthreads();
    if (n < N) start[n] = base_s + sc[tid] - d;  // exclusive
}

__global__ void scatter_kernel(const int* __restrict__ ei,
                               const int* __restrict__ start,
                               int* __restrict__ fill,
                               int* __restrict__ esrc,
                               int E0, int Etot) {
    const int t = blockIdx.x * blockDim.x + threadIdx.x;
    if (t >= Etot) return;
    int src, dst;
    if (t < E0) { src = ei[t]; dst = ei[E0 + t]; }
    else        { src = dst = t - E0; }
    const int pos = start[dst] + atomicAdd(&fill[dst], 1);
    esrc[pos] = src;
}

// ---------------------------------------------------------------------------
// 3) Fused attention + softmax + aggregation (unchanged — verified R9-R11).
//    One wave per node; lane l owns channels (2l, 2l+1).  bf16x2 xl gather
//    with SGPR-base addressing; DPP 4-stage reduce + ds_swizzle broadcast.
// ---------------------------------------------------------------------------
template <int CTRL>
__device__ __forceinline__ float dpp_add(float v) {
    const int t = __builtin_amdgcn_update_dpp(
        0, __float_as_int(v), CTRL, 0xF, 0xF, true);
    return v + __int_as_float(t);
}

__device__ __forceinline__ float row_sum_bcast(float c) {
    c = dpp_add<0x111>(c);  // row_shr:1
    c = dpp_add<0x112>(c);  // row_shr:2
    c = dpp_add<0x114>(c);  // row_shr:4
    c = dpp_add<0x118>(c);  // row_shr:8 -> lane15 of each 16-row = row sum
    return __int_as_float(
        __builtin_amdgcn_ds_swizzle(__float_as_int(c), 0x01F0));  // bcast lane15
}

__global__ void __launch_bounds__(256)
fused_agg_kernel(const unsigned short* __restrict__ xlb,
                 const float* __restrict__ xr,
                 const float* __restrict__ att,
                 const float* __restrict__ bias,
                 const int* __restrict__ esrc,
                 const int* __restrict__ start,
                 const int* __restrict__ deg,
                 float* __restrict__ out, int N, int EtotM1) {
    __shared__ int les_all[4][68];
    const int wid = threadIdx.x >> 6;
    const int lane = threadIdx.x & 63;
    const int n = blockIdx.x * 4 + wid;
    if (n >= N) return;
    int* les = les_all[wid];

    const int ch = lane * 2;  // channel pair; head = lane>>4 = DPP row
    const float2 xr2 = *(const float2*)&xr[(size_t)n * HC + ch];
    const float2 at2 = *(const float2*)&att[ch];
    const float au0 = at2.x * LOG2E, au1 = at2.y * LOG2E;
    const float an0 = au0 * NEG_SLOPE, an1 = au1 * NEG_SLOPE;
    const int s0 = start[n];
    const int d = deg[n];                      // >= 1 (self-loop)

    float sum = 0.f, ax = 0.f, ay = 0.f;

    for (int jb = 0; jb < d; jb += 64) {
        const int cnt = min(64, d - jb);
        les[lane] = esrc[min(s0 + jb + lane, EtotM1)];  // clamped: valid id
        if (lane < 4) les[64 + lane] = 0;               // pad for prefetch

        const int sA0 = __builtin_amdgcn_readfirstlane(les[0]);
        const int sB0 = __builtin_amdgcn_readfirstlane(les[1]);
        unsigned pkA = *(const unsigned*)&xlb[(size_t)sA0 * HC + ch];
        unsigned pkB = *(const unsigned*)&xlb[(size_t)sB0 * HC + ch];

        int j = 0;
        for (; j + 1 < cnt; j += 2) {
            const int sC = __builtin_amdgcn_readfirstlane(les[j + 2]);
            const int sD = __builtin_amdgcn_readfirstlane(les[j + 3]);
            const unsigned pkC = *(const unsigned*)&xlb[(size_t)sC * HC + ch];
            const unsigned pkD = *(const unsigned*)&xlb[(size_t)sD * HC + ch];

            // edge A
            {
                const float vx = __uint_as_float(pkA << 16);
                const float vy = __uint_as_float(pkA & 0xFFFF0000u);
                const float sx = vx + xr2.x;
                const float sy = vy + xr2.y;
                float c = ((sx > 0.f) ? au0 : an0) * sx;
                c = fmaf(((sy > 0.f) ? au1 : an1), sy, c);
                const float p = exp2f(row_sum_bcast(c));
                sum += p;
                ax = fmaf(p, vx, ax);
                ay = fmaf(p, vy, ay);
            }
            // edge B
            {
                const float vx = __uint_as_float(pkB << 16);
                const float vy = __uint_as_float(pkB & 0xFFFF0000u);
                const float sx = vx + xr2.x;
                const float sy = vy + xr2.y;
                float c = ((sx > 0.f) ? au0 : an0) * sx;
                c = fmaf(((sy > 0.f) ? au1 : an1), sy, c);
                const float p = exp2f(row_sum_bcast(c));
                sum += p;
                ax = fmaf(p, vx, ax);
                ay = fmaf(p, vy, ay);
            }
            pkA = pkC; pkB = pkD;
        }
        if (j < cnt) {  // tail edge
            const float vx = __uint_as_float(pkA << 16);
            const float vy = __uint_as_float(pkA & 0xFFFF0000u);
            const float sx = vx + xr2.x;
            const float sy = vy + xr2.y;
            float c = ((sx > 0.f) ? au0 : an0) * sx;
            c = fmaf(((sy > 0.f) ? au1 : an1), sy, c);
            const float p = exp2f(row_sum_bcast(c));
            sum += p;
            ax = fmaf(p, vx, ax);
            ay = fmaf(p, vy, ay);
        }
    }
    const float inv = 1.f / (sum + 1e-16f);
    const float2 b2 = *(const float2*)&bias[ch];
    float2 o;
    o.x = fmaf(ax, inv, b2.x);
    o.y = fmaf(ay, inv, b2.y);
    *(float2*)&out[(size_t)n * HC + ch] = o;
}

// ---------------------------------------------------------------------------
extern "C" void kernel_launch(void* const* d_in, const int* in_sizes, int n_in,
                              void* d_out, int out_size, void* d_ws, size_t ws_size,
                              hipStream_t stream) {
    const float* x    = (const float*)d_in[0];
    const int*   ei   = (const int*)d_in[1];   // harness delivers int inputs as int32
    const float* Wl   = (const float*)d_in[2];
    const float* Wr   = (const float*)d_in[3];
    const float* att  = (const float*)d_in[4];
    const float* bias = (const float*)d_in[5];
    float* out        = (float*)d_out;

    const int N    = in_sizes[0] / IN_F;   // 50000
    const int E0   = in_sizes[1] / 2;      // 800000
    const int Etot = E0 + N;               // 850000

    char* base = (char*)d_ws;
    unsigned short* xlb = (unsigned short*)base; base += (size_t)N * HC * sizeof(unsigned short);
    float* xr   = (float*)base;        base += (size_t)N * HC * sizeof(float);
    int*   esrc = (int*)base;          base += (size_t)Etot * sizeof(int);
    // contiguous zero region: deg | fill | cursor
    int*   deg  = (int*)base;          base += (size_t)N * sizeof(int);
    int*   fill = (int*)base;          base += (size_t)N * sizeof(int);
    unsigned int* cursor = (unsigned int*)base; base += sizeof(unsigned int);
    int*   strt = (int*)base;          base += (size_t)N * sizeof(int);
    unsigned short* Wt = (unsigned short*)base;

    prep_kernel<<<400, 256, 0, stream>>>(Wl, Wr, Wt, deg, 2 * N + 1);
    proj_kernel<<<(N + 63) / 64, 256, 0, stream>>>(x, Wt, xlb, xr, N,
                                                   ei, deg, E0, Etot);
    alloc_kernel<<<(N + 255) / 256, 256, 0, stream>>>(deg, strt, cursor, N);
    scatter_kernel<<<(Etot + 255) / 256, 256, 0, stream>>>(ei, strt, fill, esrc, E0, Etot);

    fused_agg_kernel<<<(N + 3) / 4, 256, 0, stream>>>(xlb, xr, att, bias, esrc, strt, deg,
                                                      out, N, Etot - 1);
}